// Round 6
// baseline (804.624 us; speedup 1.0000x reference)
//
#include <hip/hip_runtime.h>
#include <math.h>

#define B_   64
#define N_   512
#define E_   524288
#define BN_  32768
#define K1_  410
#define K2_  328
#define NK_  26240   // B_*K1_
#define KC_  25      // layer-1 K chunk

__device__ __forceinline__ float lrelu(float x) { return x > 0.f ? x : 0.2f * x; }

// ---------------------------------------------------------------- norms
__global__ __launch_bounds__(256) void norm_kernel(const float* __restrict__ p1,
                                                   const float* __restrict__ p2,
                                                   float* __restrict__ norms) {
    __shared__ float r1[256], r2[256];
    int t = threadIdx.x;
    float a = p1[t], b = p2[t];
    r1[t] = a * a; r2[t] = b * b;
    for (int o = 128; o > 0; o >>= 1) {
        __syncthreads();
        if (t < o) { r1[t] += r1[t + o]; r2[t] += r2[t + o]; }
    }
    __syncthreads();
    if (t == 0) { norms[0] = sqrtf(r1[0]); norms[1] = sqrtf(r2[0]); }
}

// ---------------------------------------------------------------- generic scan (exclusive) over NSEG counters
template <int NSEG>
__global__ __launch_bounds__(1024) void scan_kernel(int* __restrict__ cnt, int* __restrict__ offsets)
{
    __shared__ int part[1024];
    int t = threadIdx.x;
    const int CH = (NSEG + 1023) / 1024;
    int base = t * CH;
    int sum = 0;
    for (int i = 0; i < CH; ++i) { int gi = base + i; if (gi < NSEG) sum += cnt[gi]; }
    part[t] = sum;
    __syncthreads();
    for (int o = 1; o < 1024; o <<= 1) {
        int v = (t >= o) ? part[t - o] : 0;
        __syncthreads();
        part[t] += v;
        __syncthreads();
    }
    int run = (t == 0) ? 0 : part[t - 1];
    for (int i = 0; i < CH; ++i) {
        int gi = base + i;
        if (gi < NSEG) { offsets[gi] = run; run += cnt[gi]; cnt[gi] = 0; }
    }
    if (t == 1023) offsets[NSEG] = part[1023];
}

// ---------------------------------------------------------------- node-CSR (dst over ALL edges)
__global__ __launch_bounds__(256) void count_node_kernel(const int* __restrict__ dstG,
                                                         int* __restrict__ cnt_node)
{
    int e = blockIdx.x * blockDim.x + threadIdx.x;
    atomicAdd(&cnt_node[dstG[e]], 1);
}

__global__ __launch_bounds__(256) void fill_node_kernel(const int* __restrict__ dstG,
                                                        const int* __restrict__ offs_node,
                                                        int* __restrict__ cnt_node,
                                                        int* __restrict__ csr_e)
{
    int e = blockIdx.x * blockDim.x + threadIdx.x;
    int d = dstG[e];
    int p = offs_node[d] + atomicAdd(&cnt_node[d], 1);
    csr_e[p] = e;
}

// ---------------------------------------------------------------- fused edge MLP + GINE segmented aggregate
// 64 dst-SORTED edges per block; all LDS operand tiles k-major for b128/b64 reads.
__global__ __launch_bounds__(256) void edge_mlp_agg_kernel(
    const float* __restrict__ edge_attr, const int* __restrict__ srcG,
    const int* __restrict__ dstG, const int* __restrict__ csr_e,
    const float* __restrict__ x,
    const float* __restrict__ W1, const float* __restrict__ b1,
    const float* __restrict__ W2, const float* __restrict__ b2,
    float* __restrict__ agg)
{
    __shared__ float bufAT[KC_][68];  // attr chunk, k-major (pad 68 for write conflicts, 272B rows = 16B aligned)
    __shared__ float w1cT[KC_][64];   // W1 chunk, k-major (256B rows)
    __shared__ float ea1T[64][66];    // layer-1 out, k-major [k][edge]; later reused as msg [edge][col]
    __shared__ float w2s[64][32];     // W2 k-major
    __shared__ float b2s[32];
    __shared__ int   srcs[64], dsts[64], eid_s[64];

    int tid = threadIdx.x;
    int eb  = blockIdx.x * 64;

    if (tid < 64) {
        int e = csr_e[eb + tid];
        eid_s[tid] = e;
        srcs[tid]  = srcG[e];
        dsts[tid]  = dstG[e];
    }
    for (int i = tid; i < 64 * 32; i += 256) w2s[i >> 5][i & 31] = W2[i];
    if (tid >= 192 && tid < 224) b2s[tid - 192] = b2[tid - 192];

    int tx = tid & 15, ty = tid >> 4;
    float b1v[4];
#pragma unroll
    for (int j = 0; j < 4; ++j) b1v[j] = b1[tx * 4 + j];

    float acc[4][4] = {};
    __syncthreads();

    // ---- layer 1, K chunked (4 x 25), k-major tiles
    for (int kc = 0; kc < 100; kc += KC_) {
        for (int i = tid; i < 64 * KC_; i += 256) {
            int e = i / KC_, k = i - e * KC_;           // coalesced global (consecutive k of one row)
            bufAT[k][e] = edge_attr[(size_t)eid_s[e] * 100 + kc + k];
        }
        for (int i = tid; i < KC_ * 64; i += 256)
            w1cT[i >> 6][i & 63] = W1[(size_t)(kc + (i >> 6)) * 64 + (i & 63)];
        __syncthreads();
#pragma unroll 5
        for (int k = 0; k < KC_; ++k) {
            float4 a4 = *(const float4*)&bufAT[k][ty * 4];   // 4 edges
            float4 w4 = *(const float4*)&w1cT[k][tx * 4];    // 4 cols
            float a[4] = { a4.x, a4.y, a4.z, a4.w };
            float w[4] = { w4.x, w4.y, w4.z, w4.w };
#pragma unroll
            for (int i = 0; i < 4; ++i)
#pragma unroll
                for (int j = 0; j < 4; ++j) acc[i][j] += a[i] * w[j];
        }
        __syncthreads();
    }
    // store layer-1 output transposed: ea1T[col][edge]
#pragma unroll
    for (int i = 0; i < 4; ++i)
#pragma unroll
        for (int j = 0; j < 4; ++j)
            ea1T[tx * 4 + j][ty * 4 + i] = fmaxf(acc[i][j] + b1v[j], 0.f);
    __syncthreads();

    // ---- layer 2: 64x32, K=64; thread: 2 edges x 4 cols; k-major reads
    int e0 = (tid >> 3) * 2;       // even
    int c0 = (tid & 7) * 4;
    float acc2[2][4] = {};
    for (int k = 0; k < 64; ++k) {
        float2 a2 = *(const float2*)&ea1T[k][e0];        // 2 edges (8B aligned: stride 66, e0 even)
        float4 w4 = *(const float4*)&w2s[k][c0];         // 4 cols
        float w[4] = { w4.x, w4.y, w4.z, w4.w };
#pragma unroll
        for (int j = 0; j < 4; ++j) {
            acc2[0][j] += a2.x * w[j]; acc2[1][j] += a2.y * w[j];
        }
    }
    __syncthreads();   // all ea1T reads done; safe to overwrite with msg [edge][col]
#pragma unroll
    for (int r = 0; r < 2; ++r) {
        int e = e0 + r, s = srcs[e];
        const float4 xv = *(const float4*)(x + (size_t)s * 32 + c0);
        float xa[4] = { xv.x, xv.y, xv.z, xv.w };
#pragma unroll
        for (int j = 0; j < 4; ++j) {
            float ea2 = fmaxf(acc2[r][j] + b2s[c0 + j], 0.f);
            ea1T[e][c0 + j] = fmaxf(xa[j] + ea2, 0.f);   // msg
        }
    }
    __syncthreads();

    // ---- segmented reduction over same-dst runs (sorted): 32 groups x 8 threads
    int grp = tid >> 3, gc = (tid & 7) * 4;
    for (int e = grp; e < 64; e += 32) {
        if (e > 0 && dsts[e] == dsts[e - 1]) continue;   // not a run head
        int d = dsts[e];
        float s0 = 0.f, s1 = 0.f, s2 = 0.f, s3 = 0.f;
        for (int j = e; j < 64 && dsts[j] == d; ++j) {
            float2 p0 = *(const float2*)&ea1T[j][gc];
            float2 p1 = *(const float2*)&ea1T[j][gc + 2];
            s0 += p0.x; s1 += p0.y; s2 += p1.x; s3 += p1.y;
        }
        atomicAdd(&agg[(size_t)d * 32 + gc + 0], s0);
        atomicAdd(&agg[(size_t)d * 32 + gc + 1], s1);
        atomicAdd(&agg[(size_t)d * 32 + gc + 2], s2);
        atomicAdd(&agg[(size_t)d * 32 + gc + 3], s3);
    }
}

// ---------------------------------------------------------------- generic tiled GEMM: C = act(A(+A2) @ W + bias)
template <int ACT, bool HASBIAS, bool HASA2>
__global__ __launch_bounds__(256) void gemm_tile(
    const float* __restrict__ A, const float* __restrict__ A2,
    const float* __restrict__ W, const float* __restrict__ bias,
    float* __restrict__ C, int M, int N, int K)
{
    __shared__ float As[16][68];
    __shared__ float Ws[16][68];
    int tid = threadIdx.x;
    int tx = tid & 15, ty = tid >> 4;
    int mb = blockIdx.y * 64, nb = blockIdx.x * 64;
    float acc[4][4] = {};

    for (int kt = 0; kt < K; kt += 16) {
        int k = tid & 15, m4 = tid >> 4;
#pragma unroll
        for (int i = 0; i < 4; ++i) {
            int m = m4 * 4 + i;
            int gk = kt + k;
            float v = 0.f;
            if (gk < K) {
                size_t gi = (size_t)(mb + m) * K + gk;
                v = A[gi];
                if (HASA2) v += A2[gi];
            }
            As[k][m] = v;
        }
        int n = tid & 63;
#pragma unroll
        for (int i = 0; i < 4; ++i) {
            int kk = (tid >> 6) * 4 + i;
            int gk = kt + kk;
            Ws[kk][n] = (gk < K) ? W[(size_t)gk * N + nb + n] : 0.f;
        }
        __syncthreads();
#pragma unroll
        for (int k2 = 0; k2 < 16; ++k2) {
            float4 a4 = *(const float4*)&As[k2][ty * 4];
            float4 w4 = *(const float4*)&Ws[k2][tx * 4];
            float a[4] = { a4.x, a4.y, a4.z, a4.w };
            float w[4] = { w4.x, w4.y, w4.z, w4.w };
#pragma unroll
            for (int i = 0; i < 4; ++i)
#pragma unroll
                for (int j = 0; j < 4; ++j) acc[i][j] += a[i] * w[j];
        }
        __syncthreads();
    }
#pragma unroll
    for (int i = 0; i < 4; ++i) {
        int m = mb + ty * 4 + i;
#pragma unroll
        for (int j = 0; j < 4; ++j) {
            int n = nb + tx * 4 + j;
            float v = acc[i][j];
            if (HASBIAS) v += bias[n];
            if (ACT == 1) v = fmaxf(v, 0.f);
            C[(size_t)m * N + n] = v;
        }
    }
}

// ---------------------------------------------------------------- scores: s[i] = tanh(dot(P[i,:256], w)/norm)
__global__ __launch_bounds__(256) void scores_kernel(const float* __restrict__ P,
                                                     const float* __restrict__ w,
                                                     const float* __restrict__ norms, int nidx,
                                                     float* __restrict__ s, int R)
{
    int wid  = (blockIdx.x * blockDim.x + threadIdx.x) >> 6;
    int lane = threadIdx.x & 63;
    if (wid >= R) return;
    float acc = 0.f;
#pragma unroll
    for (int r = 0; r < 4; ++r) {
        int d = r * 64 + lane;
        acc += P[(size_t)wid * 256 + d] * w[d];
    }
    for (int o = 32; o > 0; o >>= 1) acc += __shfl_xor(acc, o);
    if (lane == 0) s[wid] = tanhf(acc / norms[nidx]);
}

// ---------------------------------------------------------------- bitonic sort (512, descending, idx-asc tiebreak)
__device__ void bitonic_desc512(float* val, int* idx, int t) {
    for (int k = 2; k <= 512; k <<= 1) {
        for (int j = k >> 1; j > 0; j >>= 1) {
            __syncthreads();
            int ixj = t ^ j;
            if (ixj > t) {
                float v0 = val[t], v1 = val[ixj];
                int   i0 = idx[t], i1 = idx[ixj];
                bool before = (v0 > v1) || (v0 == v1 && i0 < i1);
                bool dir = ((t & k) == 0);
                bool doswap = dir ? (!before) : before;
                if (doswap) { val[t] = v1; val[ixj] = v0; idx[t] = i1; idx[ixj] = i0; }
            }
        }
    }
    __syncthreads();
}

__global__ __launch_bounds__(512) void topk1_kernel(const float* __restrict__ s,
                                                    float* __restrict__ topval,
                                                    int* __restrict__ topnode,
                                                    int* __restrict__ kept,
                                                    int* __restrict__ newid)
{
    __shared__ float val[512];
    __shared__ int   idx[512];
    int b = blockIdx.x, t = threadIdx.x;
    val[t] = s[b * N_ + t]; idx[t] = t;
    bitonic_desc512(val, idx, t);
    if (t < K1_) {
        int node = b * N_ + idx[t];
        int orow = b * K1_ + t;
        topnode[orow] = node;
        topval[orow]  = val[t];
        kept[node]  = 1;
        newid[node] = orow;
    }
}

// ---------------------------------------------------------------- hp[i,:] = h[topnode[i],:]*topval[i]
__global__ __launch_bounds__(256) void gather_scale_kernel(const float* __restrict__ h,
                                                           const int* __restrict__ topnode,
                                                           const float* __restrict__ topval,
                                                           float* __restrict__ hp)
{
    int gid = blockIdx.x * blockDim.x + threadIdx.x;   // NK_*64 threads
    int row = gid >> 6, q = gid & 63;
    float4 v = *(const float4*)(h + (size_t)topnode[row] * 256 + q * 4);
    float tv = topval[row];
    float4 o; o.x = v.x * tv; o.y = v.y * tv; o.z = v.z * tv; o.w = v.w * tv;
    *(float4*)(hp + (size_t)row * 256 + q * 4) = o;
}

// ---------------------------------------------------------------- readout 1: zbuf[b] = concat(max, mean); 4 row-groups
__global__ __launch_bounds__(1024) void readout1_kernel(const float* __restrict__ hp,
                                                        float* __restrict__ zbuf)
{
    __shared__ float rmx[1024], rsm[1024];
    int b = blockIdx.x, tid = threadIdx.x;
    int c = tid & 255, g = tid >> 8;
    float mx = -INFINITY, sm = 0.f;
    for (int j = g; j < K1_; j += 4) {
        float v = hp[((size_t)b * K1_ + j) * 256 + c];
        mx = fmaxf(mx, v); sm += v;
    }
    rmx[tid] = mx; rsm[tid] = sm;
    __syncthreads();
    if (tid < 512) { rmx[tid] = fmaxf(rmx[tid], rmx[tid + 512]); rsm[tid] += rsm[tid + 512]; }
    __syncthreads();
    if (tid < 256) {
        zbuf[b * 512 + tid]       = fmaxf(rmx[tid], rmx[tid + 256]);
        zbuf[b * 512 + 256 + tid] = (rsm[tid] + rsm[tid + 256]) / (float)K1_;
    }
}

// ---------------------------------------------------------------- attention coefficients
__global__ __launch_bounds__(256) void attcoef_kernel(const float* __restrict__ xl,
                                                      const float* __restrict__ att_src,
                                                      const float* __restrict__ att_dst,
                                                      float* __restrict__ a_src,
                                                      float* __restrict__ a_dst)
{
    int wid  = (blockIdx.x * blockDim.x + threadIdx.x) >> 6;
    int lane = threadIdx.x & 63;
    if (wid >= NK_) return;
    float vs[4], vd[4];
#pragma unroll
    for (int r = 0; r < 4; ++r) {
        int d = r * 64 + lane;
        float v = xl[(size_t)wid * 256 + d];
        vs[r] = v * att_src[d];
        vd[r] = v * att_dst[d];
    }
    for (int o = 32; o > 0; o >>= 1) {
#pragma unroll
        for (int r = 0; r < 4; ++r) {
            vs[r] += __shfl_xor(vs[r], o);
            vd[r] += __shfl_xor(vd[r], o);
        }
    }
    if (lane == 0) {
#pragma unroll
        for (int r = 0; r < 4; ++r) {
            a_src[wid * 4 + r] = vs[r];
            a_dst[wid * 4 + r] = vd[r];
        }
    }
}

// ---------------------------------------------------------------- GAT CSR build (pooled graph)
__global__ __launch_bounds__(256) void count_kernel(const int* __restrict__ srcG,
                                                    const int* __restrict__ dstG,
                                                    const int* __restrict__ kept,
                                                    const int* __restrict__ newid,
                                                    int* __restrict__ cnt)
{
    int e = blockIdx.x * blockDim.x + threadIdx.x;
    int s = srcG[e], d = dstG[e];
    if (kept[s] && kept[d]) atomicAdd(&cnt[newid[d]], 1);
}

__global__ __launch_bounds__(256) void fill_kernel(const int* __restrict__ srcG,
                                                   const int* __restrict__ dstG,
                                                   const int* __restrict__ kept,
                                                   const int* __restrict__ newid,
                                                   const int* __restrict__ offsets,
                                                   int* __restrict__ cnt,
                                                   int* __restrict__ csr_src)
{
    int e = blockIdx.x * blockDim.x + threadIdx.x;
    int s = srcG[e], d = dstG[e];
    if (kept[s] && kept[d]) {
        int d1 = newid[d];
        int p = offsets[d1] + atomicAdd(&cnt[d1], 1);
        csr_src[p] = newid[s];
    }
}

// ---------------------------------------------------------------- GAT aggregation: one wave per dst node
__global__ __launch_bounds__(256) void gat_agg_kernel(const float* __restrict__ xl,
                                                      const float* __restrict__ a_src,
                                                      const float* __restrict__ a_dst,
                                                      const int* __restrict__ offsets,
                                                      const int* __restrict__ csr_src,
                                                      const float* __restrict__ gat_b,
                                                      float* __restrict__ g)
{
    int wid  = (blockIdx.x * blockDim.x + threadIdx.x) >> 6;
    int lane = threadIdx.x & 63;
    if (wid >= NK_) return;
    int off0 = offsets[wid], off1 = offsets[wid + 1];

    float4 ad = *(const float4*)(a_dst + (size_t)wid * 4);
    float4 asf = *(const float4*)(a_src + (size_t)wid * 4);
    float adv[4] = { ad.x, ad.y, ad.z, ad.w };
    float lsf[4] = { lrelu(asf.x + ad.x), lrelu(asf.y + ad.y),
                     lrelu(asf.z + ad.z), lrelu(asf.w + ad.w) };

    float mx[4] = { lsf[0], lsf[1], lsf[2], lsf[3] };
    for (int e = off0 + lane; e < off1; e += 64) {
        int s1 = csr_src[e];
        float4 a = *(const float4*)(a_src + (size_t)s1 * 4);
        float av[4] = { a.x, a.y, a.z, a.w };
#pragma unroll
        for (int r = 0; r < 4; ++r) mx[r] = fmaxf(mx[r], lrelu(av[r] + adv[r]));
    }
    for (int o = 32; o > 0; o >>= 1)
#pragma unroll
        for (int r = 0; r < 4; ++r) mx[r] = fmaxf(mx[r], __shfl_xor(mx[r], o));

    float den[4] = {};
    for (int e = off0 + lane; e < off1; e += 64) {
        int s1 = csr_src[e];
        float4 a = *(const float4*)(a_src + (size_t)s1 * 4);
        float av[4] = { a.x, a.y, a.z, a.w };
#pragma unroll
        for (int r = 0; r < 4; ++r) den[r] += expf(lrelu(av[r] + adv[r]) - mx[r]);
    }
    for (int o = 32; o > 0; o >>= 1)
#pragma unroll
        for (int r = 0; r < 4; ++r) den[r] += __shfl_xor(den[r], o);

    float wself[4], acc[4];
#pragma unroll
    for (int r = 0; r < 4; ++r) {
        wself[r] = expf(lsf[r] - mx[r]);
        den[r] += wself[r];
    }
#pragma unroll
    for (int r = 0; r < 4; ++r)
        acc[r] = (wself[r] / den[r]) * xl[(size_t)wid * 256 + r * 64 + lane];

    for (int e = off0; e < off1; ++e) {
        int s1 = csr_src[e];
        float4 a = *(const float4*)(a_src + (size_t)s1 * 4);
        float av[4] = { a.x, a.y, a.z, a.w };
#pragma unroll
        for (int r = 0; r < 4; ++r) {
            float w = expf(lrelu(av[r] + adv[r]) - mx[r]) / den[r];
            acc[r] += w * xl[(size_t)s1 * 256 + r * 64 + lane];
        }
    }
#pragma unroll
    for (int r = 0; r < 4; ++r) {
        int d = r * 64 + lane;
        g[(size_t)wid * 256 + d] = fmaxf(acc[r] + gat_b[d], 0.f);
    }
}

// ---------------------------------------------------------------- topk2 + readout2 (adds into zbuf); 2 row-groups
__global__ __launch_bounds__(512) void topk2_readout_kernel(const float* __restrict__ s2,
                                                            const float* __restrict__ g,
                                                            float* __restrict__ zbuf)
{
    __shared__ float val[512];
    __shared__ int   idx[512];
    __shared__ float rmx2[512], rsm2[512];
    int b = blockIdx.x, t = threadIdx.x;
    val[t] = (t < K1_) ? s2[b * K1_ + t] : -INFINITY;
    idx[t] = t;
    bitonic_desc512(val, idx, t);
    int c = t & 255, gg = t >> 8;
    float mx = -INFINITY, sm = 0.f;
    for (int j = gg; j < K2_; j += 2) {
        int row = b * K1_ + idx[j];
        float v = g[(size_t)row * 256 + c] * val[j];
        mx = fmaxf(mx, v); sm += v;
    }
    rmx2[t] = mx; rsm2[t] = sm;
    __syncthreads();
    if (t < 256) {
        zbuf[b * 512 + t]       += fmaxf(rmx2[t], rmx2[t + 256]);
        zbuf[b * 512 + 256 + t] += (rsm2[t] + rsm2[t + 256]) / (float)K2_;
    }
}

// ---------------------------------------------------------------- head
__global__ __launch_bounds__(128) void head_kernel(const float* __restrict__ zbuf,
                                                   const float* __restrict__ l1w, const float* __restrict__ l1b,
                                                   const float* __restrict__ l2w, const float* __restrict__ l2b,
                                                   const float* __restrict__ l3w, const float* __restrict__ l3b,
                                                   float* __restrict__ out)
{
    __shared__ float zs[512];
    __shared__ float h1s[128];
    __shared__ float h2s[64];
    __shared__ float os[2];
    int b = blockIdx.x, t = threadIdx.x;
    for (int i = t; i < 512; i += 128) zs[i] = zbuf[b * 512 + i];
    __syncthreads();
    float acc = l1b[t];
    for (int k = 0; k < 512; ++k) acc += zs[k] * l1w[k * 128 + t];
    h1s[t] = fmaxf(acc, 0.f);
    __syncthreads();
    if (t < 64) {
        float a2 = l2b[t];
        for (int k = 0; k < 128; ++k) a2 += h1s[k] * l2w[k * 64 + t];
        h2s[t] = fmaxf(a2, 0.f);
    }
    __syncthreads();
    if (t < 2) {
        float a3 = l3b[t];
        for (int k = 0; k < 64; ++k) a3 += h2s[k] * l3w[k * 2 + t];
        os[t] = a3;
    }
    __syncthreads();
    if (t == 0) {
        float m = fmaxf(os[0], os[1]);
        float lse = m + logf(expf(os[0] - m) + expf(os[1] - m));
        out[b * 2 + 0] = os[0] - lse;
        out[b * 2 + 1] = os[1] - lse;
    }
}

// ================================================================ launch
extern "C" void kernel_launch(void* const* d_in, const int* in_sizes, int n_in,
                              void* d_out, int out_size, void* d_ws, size_t ws_size,
                              hipStream_t stream)
{
    const float* x         = (const float*)d_in[0];
    const int*   eidx      = (const int*)d_in[1];
    const float* edge_attr = (const float*)d_in[3];
    const float* dec1_w    = (const float*)d_in[4];
    const float* dec1_b    = (const float*)d_in[5];
    const float* dec2_w    = (const float*)d_in[6];
    const float* dec2_b    = (const float*)d_in[7];
    const float* mlp1_w    = (const float*)d_in[8];
    const float* mlp1_b    = (const float*)d_in[9];
    const float* mlp2_w    = (const float*)d_in[10];
    const float* mlp2_b    = (const float*)d_in[11];
    const float* pool1_w   = (const float*)d_in[12];
    const float* gat_w     = (const float*)d_in[13];
    const float* att_src   = (const float*)d_in[14];
    const float* att_dst   = (const float*)d_in[15];
    const float* gat_b     = (const float*)d_in[16];
    const float* pool2_w   = (const float*)d_in[17];
    const float* lin1_w    = (const float*)d_in[18];
    const float* lin1_b    = (const float*)d_in[19];
    const float* lin2_w    = (const float*)d_in[20];
    const float* lin2_b    = (const float*)d_in[21];
    const float* lin3_w    = (const float*)d_in[22];
    const float* lin3_b    = (const float*)d_in[23];
    const int* srcG = eidx;
    const int* dstG = eidx + E_;
    float* out = (float*)d_out;

    // ---- workspace layout
    char* base = (char*)d_ws;
    size_t o = 0;
    auto alloc = [&](size_t bytes) { size_t r = o; o = (o + bytes + 255) & ~(size_t)255; return r; };
    size_t agg_off    = alloc((size_t)BN_ * 32 * 4);
    size_t cntn_off   = alloc((size_t)BN_ * 4);        // node-CSR counters
    size_t cnt_off    = alloc((size_t)NK_ * 4);        // GAT-CSR counters
    size_t kept_off   = alloc((size_t)BN_ * 4);
    size_t zero_bytes = o;                             // agg + cnt_node + cnt + kept contiguous
    size_t newid_off  = alloc((size_t)BN_ * 4);
    size_t offsn_off  = alloc((size_t)(BN_ + 1) * 4);
    size_t csre_off   = alloc((size_t)E_ * 4);
    size_t h_off      = alloc((size_t)BN_ * 256 * 4);  // also g
    size_t hp_off     = alloc((size_t)NK_ * 256 * 4);
    size_t xl_off     = alloc((size_t)NK_ * 256 * 4);  // also t1 [BN_,128]
    size_t s_off      = alloc((size_t)BN_ * 4);        // also s2
    size_t tnode_off  = alloc((size_t)NK_ * 4);
    size_t tval_off   = alloc((size_t)NK_ * 4);
    size_t offs_off   = alloc((size_t)(NK_ + 1) * 4);
    size_t csr_off    = alloc((size_t)E_ * 4);
    size_t zbuf_off   = alloc((size_t)B_ * 512 * 4);
    size_t asrc_off   = alloc((size_t)NK_ * 4 * 4);
    size_t adst_off   = alloc((size_t)NK_ * 4 * 4);
    size_t norm_off   = alloc(256);
    if (o > ws_size) return;   // workspace too small -> fail validation visibly

    float* agg      = (float*)(base + agg_off);
    int*   cnt_node = (int*)  (base + cntn_off);
    int*   cnt      = (int*)  (base + cnt_off);
    int*   kept     = (int*)  (base + kept_off);
    int*   newid    = (int*)  (base + newid_off);
    int*   offs_n   = (int*)  (base + offsn_off);
    int*   csr_e    = (int*)  (base + csre_off);
    float* h        = (float*)(base + h_off);
    float* g        = h;
    float* hp       = (float*)(base + hp_off);
    float* xl       = (float*)(base + xl_off);
    float* t1       = xl;
    float* s        = (float*)(base + s_off);
    int*   tnode    = (int*)  (base + tnode_off);
    float* tval     = (float*)(base + tval_off);
    int*   offs     = (int*)  (base + offs_off);
    int*   csr      = (int*)  (base + csr_off);
    float* zbuf     = (float*)(base + zbuf_off);
    float* a_src    = (float*)(base + asrc_off);
    float* a_dst    = (float*)(base + adst_off);
    float* norms    = (float*)(base + norm_off);

    hipMemsetAsync(d_ws, 0, zero_bytes, stream);

    norm_kernel<<<1, 256, 0, stream>>>(pool1_w, pool2_w, norms);

    // node-CSR over ALL edges (dst-sorted permutation)
    count_node_kernel<<<E_ / 256, 256, 0, stream>>>(dstG, cnt_node);
    scan_kernel<BN_><<<1, 1024, 0, stream>>>(cnt_node, offs_n);
    fill_node_kernel<<<E_ / 256, 256, 0, stream>>>(dstG, offs_n, cnt_node, csr_e);

    // fused edge MLP + GINE aggregate (dst-sorted, few atomics)
    edge_mlp_agg_kernel<<<E_ / 64, 256, 0, stream>>>(edge_attr, srcG, dstG, csr_e, x,
                                                     dec1_w, dec1_b, dec2_w, dec2_b, agg);

    // MLP1: t1 = relu((x+agg) @ mlp1_w + b)   [BN_,128]
    gemm_tile<1, true, true><<<dim3(128 / 64, BN_ / 64), 256, 0, stream>>>(
        x, agg, mlp1_w, mlp1_b, t1, BN_, 128, 32);
    // MLP2: h = relu(t1 @ mlp2_w + b)         [BN_,256]
    gemm_tile<1, true, false><<<dim3(256 / 64, BN_ / 64), 256, 0, stream>>>(
        t1, nullptr, mlp2_w, mlp2_b, h, BN_, 256, 128);

    scores_kernel<<<BN_ / 4, 256, 0, stream>>>(h, pool1_w, norms, 0, s, BN_);
    topk1_kernel<<<B_, 512, 0, stream>>>(s, tval, tnode, kept, newid);
    gather_scale_kernel<<<(NK_ * 64) / 256, 256, 0, stream>>>(h, tnode, tval, hp);
    readout1_kernel<<<B_, 1024, 0, stream>>>(hp, zbuf);

    // GAT transform: xl = hp @ gat_w          [NK_,256]
    gemm_tile<0, false, false><<<dim3(256 / 64, NK_ / 64), 256, 0, stream>>>(
        hp, nullptr, gat_w, nullptr, xl, NK_, 256, 256);
    attcoef_kernel<<<NK_ / 4, 256, 0, stream>>>(xl, att_src, att_dst, a_src, a_dst);

    count_kernel<<<E_ / 256, 256, 0, stream>>>(srcG, dstG, kept, newid, cnt);
    scan_kernel<NK_><<<1, 1024, 0, stream>>>(cnt, offs);
    fill_kernel<<<E_ / 256, 256, 0, stream>>>(srcG, dstG, kept, newid, offs, cnt, csr);

    gat_agg_kernel<<<NK_ / 4, 256, 0, stream>>>(xl, a_src, a_dst, offs, csr, gat_b, g);

    scores_kernel<<<NK_ / 4, 256, 0, stream>>>(g, pool2_w, norms, 1, s, NK_);
    topk2_readout_kernel<<<B_, 512, 0, stream>>>(s, g, zbuf);

    head_kernel<<<B_, 128, 0, stream>>>(zbuf, lin1_w, lin1_b, lin2_w, lin2_b,
                                        lin3_w, lin3_b, out);
}

// Round 7
// 707.346 us; speedup vs baseline: 1.1375x; 1.1375x over previous
//
#include <hip/hip_runtime.h>
#include <math.h>

#define B_   64
#define N_   512
#define E_   524288
#define BN_  32768
#define K1_  410
#define K2_  328
#define NK_  26240   // B_*K1_
#define KC_  25      // layer-1 K chunk

__device__ __forceinline__ float lrelu(float x) { return x > 0.f ? x : 0.2f * x; }

// ---------------------------------------------------------------- norms
__global__ __launch_bounds__(256) void norm_kernel(const float* __restrict__ p1,
                                                   const float* __restrict__ p2,
                                                   float* __restrict__ norms) {
    __shared__ float r1[256], r2[256];
    int t = threadIdx.x;
    float a = p1[t], b = p2[t];
    r1[t] = a * a; r2[t] = b * b;
    for (int o = 128; o > 0; o >>= 1) {
        __syncthreads();
        if (t < o) { r1[t] += r1[t + o]; r2[t] += r2[t + o]; }
    }
    __syncthreads();
    if (t == 0) { norms[0] = sqrtf(r1[0]); norms[1] = sqrtf(r2[0]); }
}

// ---------------------------------------------------------------- generic scan (exclusive) over NSEG counters
template <int NSEG>
__global__ __launch_bounds__(1024) void scan_kernel(int* __restrict__ cnt, int* __restrict__ offsets)
{
    __shared__ int part[1024];
    int t = threadIdx.x;
    const int CH = (NSEG + 1023) / 1024;
    int base = t * CH;
    int sum = 0;
    for (int i = 0; i < CH; ++i) { int gi = base + i; if (gi < NSEG) sum += cnt[gi]; }
    part[t] = sum;
    __syncthreads();
    for (int o = 1; o < 1024; o <<= 1) {
        int v = (t >= o) ? part[t - o] : 0;
        __syncthreads();
        part[t] += v;
        __syncthreads();
    }
    int run = (t == 0) ? 0 : part[t - 1];
    for (int i = 0; i < CH; ++i) {
        int gi = base + i;
        if (gi < NSEG) { offsets[gi] = run; run += cnt[gi]; cnt[gi] = 0; }
    }
    if (t == 1023) offsets[NSEG] = part[1023];
}

// ---------------------------------------------------------------- node-CSR (dst over ALL edges)
__global__ __launch_bounds__(256) void count_node_kernel(const int* __restrict__ dstG,
                                                         int* __restrict__ cnt_node)
{
    int e = blockIdx.x * blockDim.x + threadIdx.x;
    atomicAdd(&cnt_node[dstG[e]], 1);
}

__global__ __launch_bounds__(256) void fill_node_kernel(const int* __restrict__ dstG,
                                                        const int* __restrict__ offs_node,
                                                        int* __restrict__ cnt_node,
                                                        int* __restrict__ csr_e)
{
    int e = blockIdx.x * blockDim.x + threadIdx.x;
    int d = dstG[e];
    int p = offs_node[d] + atomicAdd(&cnt_node[d], 1);
    csr_e[p] = e;
}

// ---------------------------------------------------------------- fused edge MLP + GINE segmented aggregate
// 64 dst-SORTED edges per block; async-STAGE split: issue chunk c+1 loads before compute(c),
// LDS-write them after the post-compute barrier (T14).
__global__ __launch_bounds__(256) void edge_mlp_agg_kernel(
    const float* __restrict__ edge_attr, const int* __restrict__ srcG,
    const int* __restrict__ dstG, const int* __restrict__ csr_e,
    const float* __restrict__ x,
    const float* __restrict__ W1, const float* __restrict__ b1,
    const float* __restrict__ W2, const float* __restrict__ b2,
    float* __restrict__ agg)
{
    __shared__ float bufAT[KC_][68];  // attr chunk, k-major
    __shared__ float w1cT[KC_][64];   // W1 chunk, k-major
    __shared__ float ea1T[64][66];    // layer-1 out k-major [col][edge]; later msg [edge][col]
    __shared__ float w2s[64][32];
    __shared__ float b2s[32];
    __shared__ int   srcs[64], dsts[64], eid_s[64];

    int tid = threadIdx.x;
    int eb  = blockIdx.x * 64;

    if (tid < 64) {
        int e = csr_e[eb + tid];
        eid_s[tid] = e;
        srcs[tid]  = srcG[e];
        dsts[tid]  = dstG[e];
    }
    for (int i = tid; i < 64 * 32; i += 256) w2s[i >> 5][i & 31] = W2[i];
    if (tid >= 192 && tid < 224) b2s[tid - 192] = b2[tid - 192];

    int tx = tid & 15, ty = tid >> 4;
    float b1v[4];
#pragma unroll
    for (int j = 0; j < 4; ++j) b1v[j] = b1[tx * 4 + j];

    float acc[4][4] = {};
    __syncthreads();   // eid_s ready

    float ra[7], rw[7];
    // issue loads for chunk kc into registers (1600 attr + 1600 w1 elems, 7 per thread)
    auto issue = [&](int kc) {
#pragma unroll
        for (int u = 0; u < 7; ++u) {
            int i = tid + u * 256;
            if (i < 1600) {
                int e = i / 25, k = i - e * 25;
                ra[u] = edge_attr[(size_t)eid_s[e] * 100 + kc + k];
                rw[u] = W1[(size_t)(kc + (i >> 6)) * 64 + (i & 63)];
            }
        }
    };
    auto lwrite = [&]() {
#pragma unroll
        for (int u = 0; u < 7; ++u) {
            int i = tid + u * 256;
            if (i < 1600) {
                int e = i / 25, k = i - e * 25;
                bufAT[k][e] = ra[u];
                w1cT[i >> 6][i & 63] = rw[u];
            }
        }
    };

    issue(0); lwrite();
    __syncthreads();

    // ---- layer 1, K chunked (4 x 25), pipelined
    for (int c = 0; c < 4; ++c) {
        if (c < 3) issue((c + 1) * KC_);       // loads in flight under compute
#pragma unroll 5
        for (int k = 0; k < KC_; ++k) {
            float4 a4 = *(const float4*)&bufAT[k][ty * 4];
            float4 w4 = *(const float4*)&w1cT[k][tx * 4];
            float a[4] = { a4.x, a4.y, a4.z, a4.w };
            float w[4] = { w4.x, w4.y, w4.z, w4.w };
#pragma unroll
            for (int i = 0; i < 4; ++i)
#pragma unroll
                for (int j = 0; j < 4; ++j) acc[i][j] += a[i] * w[j];
        }
        __syncthreads();                        // all reads of buffers done
        if (c < 3) {
            lwrite();
            __syncthreads();
        }
    }
    // store layer-1 output transposed: ea1T[col][edge]
#pragma unroll
    for (int i = 0; i < 4; ++i)
#pragma unroll
        for (int j = 0; j < 4; ++j)
            ea1T[tx * 4 + j][ty * 4 + i] = fmaxf(acc[i][j] + b1v[j], 0.f);
    __syncthreads();

    // ---- layer 2: 64x32, K=64; thread: 2 edges x 4 cols
    int e0 = (tid >> 3) * 2;       // even
    int c0 = (tid & 7) * 4;
    float acc2[2][4] = {};
    for (int k = 0; k < 64; ++k) {
        float2 a2 = *(const float2*)&ea1T[k][e0];
        float4 w4 = *(const float4*)&w2s[k][c0];
        float w[4] = { w4.x, w4.y, w4.z, w4.w };
#pragma unroll
        for (int j = 0; j < 4; ++j) {
            acc2[0][j] += a2.x * w[j]; acc2[1][j] += a2.y * w[j];
        }
    }
    __syncthreads();   // ea1T reads done; overwrite with msg [edge][col]
#pragma unroll
    for (int r = 0; r < 2; ++r) {
        int e = e0 + r, s = srcs[e];
        const float4 xv = *(const float4*)(x + (size_t)s * 32 + c0);
        float xa[4] = { xv.x, xv.y, xv.z, xv.w };
#pragma unroll
        for (int j = 0; j < 4; ++j) {
            float ea2 = fmaxf(acc2[r][j] + b2s[c0 + j], 0.f);
            ea1T[e][c0 + j] = fmaxf(xa[j] + ea2, 0.f);   // msg
        }
    }
    __syncthreads();

    // ---- segmented reduction over same-dst runs (sorted): 32 groups x 8 threads
    int grp = tid >> 3, gc = (tid & 7) * 4;
    for (int e = grp; e < 64; e += 32) {
        if (e > 0 && dsts[e] == dsts[e - 1]) continue;   // not a run head
        int d = dsts[e];
        float s0 = 0.f, s1 = 0.f, s2 = 0.f, s3 = 0.f;
        for (int j = e; j < 64 && dsts[j] == d; ++j) {
            float2 p0 = *(const float2*)&ea1T[j][gc];
            float2 p1 = *(const float2*)&ea1T[j][gc + 2];
            s0 += p0.x; s1 += p0.y; s2 += p1.x; s3 += p1.y;
        }
        atomicAdd(&agg[(size_t)d * 32 + gc + 0], s0);
        atomicAdd(&agg[(size_t)d * 32 + gc + 1], s1);
        atomicAdd(&agg[(size_t)d * 32 + gc + 2], s2);
        atomicAdd(&agg[(size_t)d * 32 + gc + 3], s3);
    }
}

// ---------------------------------------------------------------- 128x128 tiled GEMM, 8x8 microtile
// C = act(A(+A2) @ W + bias); M,N multiples of 128, K multiple of 16.
template <int ACT, bool HASBIAS, bool HASA2>
__global__ __launch_bounds__(256) void gemm_tile128(
    const float* __restrict__ A, const float* __restrict__ A2,
    const float* __restrict__ W, const float* __restrict__ bias,
    float* __restrict__ C, int M, int N, int K)
{
    __shared__ float As[16][132];
    __shared__ float Ws[16][132];
    int tid = threadIdx.x;
    int tx = tid & 15, ty = tid >> 4;
    int mb = blockIdx.y * 128, nb = blockIdx.x * 128;
    float acc[8][8] = {};

    int am = tid & 127;            // A stage: row
    int ak = (tid >> 7) * 8;       // A stage: k offset (0 or 8)
    int wk = tid >> 4;             // W stage: k row
    int wn = (tid & 15) * 8;       // W stage: col offset

    for (int kt = 0; kt < K; kt += 16) {
        // stage A tile (k-major)
        {
            const float* pa = A + (size_t)(mb + am) * K + kt + ak;
            float4 v0 = *(const float4*)(pa);
            float4 v1 = *(const float4*)(pa + 4);
            if (HASA2) {
                const float* pb = A2 + (size_t)(mb + am) * K + kt + ak;
                float4 u0 = *(const float4*)(pb);
                float4 u1 = *(const float4*)(pb + 4);
                v0.x += u0.x; v0.y += u0.y; v0.z += u0.z; v0.w += u0.w;
                v1.x += u1.x; v1.y += u1.y; v1.z += u1.z; v1.w += u1.w;
            }
            As[ak + 0][am] = v0.x; As[ak + 1][am] = v0.y;
            As[ak + 2][am] = v0.z; As[ak + 3][am] = v0.w;
            As[ak + 4][am] = v1.x; As[ak + 5][am] = v1.y;
            As[ak + 6][am] = v1.z; As[ak + 7][am] = v1.w;
        }
        // stage W tile
        {
            const float* pw = W + (size_t)(kt + wk) * N + nb + wn;
            *(float4*)&Ws[wk][wn]     = *(const float4*)(pw);
            *(float4*)&Ws[wk][wn + 4] = *(const float4*)(pw + 4);
        }
        __syncthreads();
#pragma unroll
        for (int k2 = 0; k2 < 16; ++k2) {
            float4 a0 = *(const float4*)&As[k2][ty * 8];
            float4 a1 = *(const float4*)&As[k2][ty * 8 + 4];
            float4 w0 = *(const float4*)&Ws[k2][tx * 8];
            float4 w1 = *(const float4*)&Ws[k2][tx * 8 + 4];
            float a[8] = { a0.x, a0.y, a0.z, a0.w, a1.x, a1.y, a1.z, a1.w };
            float w[8] = { w0.x, w0.y, w0.z, w0.w, w1.x, w1.y, w1.z, w1.w };
#pragma unroll
            for (int i = 0; i < 8; ++i)
#pragma unroll
                for (int j = 0; j < 8; ++j) acc[i][j] += a[i] * w[j];
        }
        __syncthreads();
    }
#pragma unroll
    for (int i = 0; i < 8; ++i) {
        int m = mb + ty * 8 + i;
        float4 o0, o1;
        float* po = &C[(size_t)m * N + nb + tx * 8];
        float r[8];
#pragma unroll
        for (int j = 0; j < 8; ++j) {
            float v = acc[i][j];
            if (HASBIAS) v += bias[nb + tx * 8 + j];
            if (ACT == 1) v = fmaxf(v, 0.f);
            r[j] = v;
        }
        o0.x = r[0]; o0.y = r[1]; o0.z = r[2]; o0.w = r[3];
        o1.x = r[4]; o1.y = r[5]; o1.z = r[6]; o1.w = r[7];
        *(float4*)(po)     = o0;
        *(float4*)(po + 4) = o1;
    }
}

// ---------------------------------------------------------------- scores: s[i] = tanh(dot(P[i,:256], w)/norm)
__global__ __launch_bounds__(256) void scores_kernel(const float* __restrict__ P,
                                                     const float* __restrict__ w,
                                                     const float* __restrict__ norms, int nidx,
                                                     float* __restrict__ s, int R)
{
    int wid  = (blockIdx.x * blockDim.x + threadIdx.x) >> 6;
    int lane = threadIdx.x & 63;
    if (wid >= R) return;
    float acc = 0.f;
#pragma unroll
    for (int r = 0; r < 4; ++r) {
        int d = r * 64 + lane;
        acc += P[(size_t)wid * 256 + d] * w[d];
    }
    for (int o = 32; o > 0; o >>= 1) acc += __shfl_xor(acc, o);
    if (lane == 0) s[wid] = tanhf(acc / norms[nidx]);
}

// ---------------------------------------------------------------- bitonic sort (512, descending, idx-asc tiebreak)
__device__ void bitonic_desc512(float* val, int* idx, int t) {
    for (int k = 2; k <= 512; k <<= 1) {
        for (int j = k >> 1; j > 0; j >>= 1) {
            __syncthreads();
            int ixj = t ^ j;
            if (ixj > t) {
                float v0 = val[t], v1 = val[ixj];
                int   i0 = idx[t], i1 = idx[ixj];
                bool before = (v0 > v1) || (v0 == v1 && i0 < i1);
                bool dir = ((t & k) == 0);
                bool doswap = dir ? (!before) : before;
                if (doswap) { val[t] = v1; val[ixj] = v0; idx[t] = i1; idx[ixj] = i0; }
            }
        }
    }
    __syncthreads();
}

__global__ __launch_bounds__(512) void topk1_kernel(const float* __restrict__ s,
                                                    float* __restrict__ topval,
                                                    int* __restrict__ topnode,
                                                    int* __restrict__ kept,
                                                    int* __restrict__ newid)
{
    __shared__ float val[512];
    __shared__ int   idx[512];
    int b = blockIdx.x, t = threadIdx.x;
    val[t] = s[b * N_ + t]; idx[t] = t;
    bitonic_desc512(val, idx, t);
    if (t < K1_) {
        int node = b * N_ + idx[t];
        int orow = b * K1_ + t;
        topnode[orow] = node;
        topval[orow]  = val[t];
        kept[node]  = 1;
        newid[node] = orow;
    }
}

// ---------------------------------------------------------------- hp[i,:] = h[topnode[i],:]*topval[i]
__global__ __launch_bounds__(256) void gather_scale_kernel(const float* __restrict__ h,
                                                           const int* __restrict__ topnode,
                                                           const float* __restrict__ topval,
                                                           float* __restrict__ hp)
{
    int gid = blockIdx.x * blockDim.x + threadIdx.x;   // NK_*64 threads
    int row = gid >> 6, q = gid & 63;
    float4 v = *(const float4*)(h + (size_t)topnode[row] * 256 + q * 4);
    float tv = topval[row];
    float4 o; o.x = v.x * tv; o.y = v.y * tv; o.z = v.z * tv; o.w = v.w * tv;
    *(float4*)(hp + (size_t)row * 256 + q * 4) = o;
}

// ---------------------------------------------------------------- readout 1: zbuf[b] = concat(max, mean); 4 row-groups
__global__ __launch_bounds__(1024) void readout1_kernel(const float* __restrict__ hp,
                                                        float* __restrict__ zbuf)
{
    __shared__ float rmx[1024], rsm[1024];
    int b = blockIdx.x, tid = threadIdx.x;
    int c = tid & 255, g = tid >> 8;
    float mx = -INFINITY, sm = 0.f;
    for (int j = g; j < K1_; j += 4) {
        float v = hp[((size_t)b * K1_ + j) * 256 + c];
        mx = fmaxf(mx, v); sm += v;
    }
    rmx[tid] = mx; rsm[tid] = sm;
    __syncthreads();
    if (tid < 512) { rmx[tid] = fmaxf(rmx[tid], rmx[tid + 512]); rsm[tid] += rsm[tid + 512]; }
    __syncthreads();
    if (tid < 256) {
        zbuf[b * 512 + tid]       = fmaxf(rmx[tid], rmx[tid + 256]);
        zbuf[b * 512 + 256 + tid] = (rsm[tid] + rsm[tid + 256]) / (float)K1_;
    }
}

// ---------------------------------------------------------------- attention coefficients
__global__ __launch_bounds__(256) void attcoef_kernel(const float* __restrict__ xl,
                                                      const float* __restrict__ att_src,
                                                      const float* __restrict__ att_dst,
                                                      float* __restrict__ a_src,
                                                      float* __restrict__ a_dst)
{
    int wid  = (blockIdx.x * blockDim.x + threadIdx.x) >> 6;
    int lane = threadIdx.x & 63;
    if (wid >= NK_) return;
    float vs[4], vd[4];
#pragma unroll
    for (int r = 0; r < 4; ++r) {
        int d = r * 64 + lane;
        float v = xl[(size_t)wid * 256 + d];
        vs[r] = v * att_src[d];
        vd[r] = v * att_dst[d];
    }
    for (int o = 32; o > 0; o >>= 1) {
#pragma unroll
        for (int r = 0; r < 4; ++r) {
            vs[r] += __shfl_xor(vs[r], o);
            vd[r] += __shfl_xor(vd[r], o);
        }
    }
    if (lane == 0) {
#pragma unroll
        for (int r = 0; r < 4; ++r) {
            a_src[wid * 4 + r] = vs[r];
            a_dst[wid * 4 + r] = vd[r];
        }
    }
}

// ---------------------------------------------------------------- GAT CSR build (pooled graph)
__global__ __launch_bounds__(256) void count_kernel(const int* __restrict__ srcG,
                                                    const int* __restrict__ dstG,
                                                    const int* __restrict__ kept,
                                                    const int* __restrict__ newid,
                                                    int* __restrict__ cnt)
{
    int e = blockIdx.x * blockDim.x + threadIdx.x;
    int s = srcG[e], d = dstG[e];
    if (kept[s] && kept[d]) atomicAdd(&cnt[newid[d]], 1);
}

__global__ __launch_bounds__(256) void fill_kernel(const int* __restrict__ srcG,
                                                   const int* __restrict__ dstG,
                                                   const int* __restrict__ kept,
                                                   const int* __restrict__ newid,
                                                   const int* __restrict__ offsets,
                                                   int* __restrict__ cnt,
                                                   int* __restrict__ csr_src)
{
    int e = blockIdx.x * blockDim.x + threadIdx.x;
    int s = srcG[e], d = dstG[e];
    if (kept[s] && kept[d]) {
        int d1 = newid[d];
        int p = offsets[d1] + atomicAdd(&cnt[d1], 1);
        csr_src[p] = newid[s];
    }
}

// ---------------------------------------------------------------- GAT aggregation: one wave per dst node
__global__ __launch_bounds__(256) void gat_agg_kernel(const float* __restrict__ xl,
                                                      const float* __restrict__ a_src,
                                                      const float* __restrict__ a_dst,
                                                      const int* __restrict__ offsets,
                                                      const int* __restrict__ csr_src,
                                                      const float* __restrict__ gat_b,
                                                      float* __restrict__ g)
{
    int wid  = (blockIdx.x * blockDim.x + threadIdx.x) >> 6;
    int lane = threadIdx.x & 63;
    if (wid >= NK_) return;
    int off0 = offsets[wid], off1 = offsets[wid + 1];

    float4 ad = *(const float4*)(a_dst + (size_t)wid * 4);
    float4 asf = *(const float4*)(a_src + (size_t)wid * 4);
    float adv[4] = { ad.x, ad.y, ad.z, ad.w };
    float lsf[4] = { lrelu(asf.x + ad.x), lrelu(asf.y + ad.y),
                     lrelu(asf.z + ad.z), lrelu(asf.w + ad.w) };

    float mx[4] = { lsf[0], lsf[1], lsf[2], lsf[3] };
    for (int e = off0 + lane; e < off1; e += 64) {
        int s1 = csr_src[e];
        float4 a = *(const float4*)(a_src + (size_t)s1 * 4);
        float av[4] = { a.x, a.y, a.z, a.w };
#pragma unroll
        for (int r = 0; r < 4; ++r) mx[r] = fmaxf(mx[r], lrelu(av[r] + adv[r]));
    }
    for (int o = 32; o > 0; o >>= 1)
#pragma unroll
        for (int r = 0; r < 4; ++r) mx[r] = fmaxf(mx[r], __shfl_xor(mx[r], o));

    float den[4] = {};
    for (int e = off0 + lane; e < off1; e += 64) {
        int s1 = csr_src[e];
        float4 a = *(const float4*)(a_src + (size_t)s1 * 4);
        float av[4] = { a.x, a.y, a.z, a.w };
#pragma unroll
        for (int r = 0; r < 4; ++r) den[r] += expf(lrelu(av[r] + adv[r]) - mx[r]);
    }
    for (int o = 32; o > 0; o >>= 1)
#pragma unroll
        for (int r = 0; r < 4; ++r) den[r] += __shfl_xor(den[r], o);

    float wself[4], acc[4];
#pragma unroll
    for (int r = 0; r < 4; ++r) {
        wself[r] = expf(lsf[r] - mx[r]);
        den[r] += wself[r];
    }
#pragma unroll
    for (int r = 0; r < 4; ++r)
        acc[r] = (wself[r] / den[r]) * xl[(size_t)wid * 256 + r * 64 + lane];

    for (int e = off0; e < off1; ++e) {
        int s1 = csr_src[e];
        float4 a = *(const float4*)(a_src + (size_t)s1 * 4);
        float av[4] = { a.x, a.y, a.z, a.w };
#pragma unroll
        for (int r = 0; r < 4; ++r) {
            float w = expf(lrelu(av[r] + adv[r]) - mx[r]) / den[r];
            acc[r] += w * xl[(size_t)s1 * 256 + r * 64 + lane];
        }
    }
#pragma unroll
    for (int r = 0; r < 4; ++r) {
        int d = r * 64 + lane;
        g[(size_t)wid * 256 + d] = fmaxf(acc[r] + gat_b[d], 0.f);
    }
}

// ---------------------------------------------------------------- topk2 + readout2 (adds into zbuf); 2 row-groups
__global__ __launch_bounds__(512) void topk2_readout_kernel(const float* __restrict__ s2,
                                                            const float* __restrict__ g,
                                                            float* __restrict__ zbuf)
{
    __shared__ float val[512];
    __shared__ int   idx[512];
    __shared__ float rmx2[512], rsm2[512];
    int b = blockIdx.x, t = threadIdx.x;
    val[t] = (t < K1_) ? s2[b * K1_ + t] : -INFINITY;
    idx[t] = t;
    bitonic_desc512(val, idx, t);
    int c = t & 255, gg = t >> 8;
    float mx = -INFINITY, sm = 0.f;
    for (int j = gg; j < K2_; j += 2) {
        int row = b * K1_ + idx[j];
        float v = g[(size_t)row * 256 + c] * val[j];
        mx = fmaxf(mx, v); sm += v;
    }
    rmx2[t] = mx; rsm2[t] = sm;
    __syncthreads();
    if (t < 256) {
        zbuf[b * 512 + t]       += fmaxf(rmx2[t], rmx2[t + 256]);
        zbuf[b * 512 + 256 + t] += (rsm2[t] + rsm2[t + 256]) / (float)K2_;
    }
}

// ---------------------------------------------------------------- head
__global__ __launch_bounds__(128) void head_kernel(const float* __restrict__ zbuf,
                                                   const float* __restrict__ l1w, const float* __restrict__ l1b,
                                                   const float* __restrict__ l2w, const float* __restrict__ l2b,
                                                   const float* __restrict__ l3w, const float* __restrict__ l3b,
                                                   float* __restrict__ out)
{
    __shared__ float zs[512];
    __shared__ float h1s[128];
    __shared__ float h2s[64];
    __shared__ float os[2];
    int b = blockIdx.x, t = threadIdx.x;
    for (int i = t; i < 512; i += 128) zs[i] = zbuf[b * 512 + i];
    __syncthreads();
    float acc = l1b[t];
    for (int k = 0; k < 512; ++k) acc += zs[k] * l1w[k * 128 + t];
    h1s[t] = fmaxf(acc, 0.f);
    __syncthreads();
    if (t < 64) {
        float a2 = l2b[t];
        for (int k = 0; k < 128; ++k) a2 += h1s[k] * l2w[k * 64 + t];
        h2s[t] = fmaxf(a2, 0.f);
    }
    __syncthreads();
    if (t < 2) {
        float a3 = l3b[t];
        for (int k = 0; k < 64; ++k) a3 += h2s[k] * l3w[k * 2 + t];
        os[t] = a3;
    }
    __syncthreads();
    if (t == 0) {
        float m = fmaxf(os[0], os[1]);
        float lse = m + logf(expf(os[0] - m) + expf(os[1] - m));
        out[b * 2 + 0] = os[0] - lse;
        out[b * 2 + 1] = os[1] - lse;
    }
}

// ================================================================ launch
extern "C" void kernel_launch(void* const* d_in, const int* in_sizes, int n_in,
                              void* d_out, int out_size, void* d_ws, size_t ws_size,
                              hipStream_t stream)
{
    const float* x         = (const float*)d_in[0];
    const int*   eidx      = (const int*)d_in[1];
    const float* edge_attr = (const float*)d_in[3];
    const float* dec1_w    = (const float*)d_in[4];
    const float* dec1_b    = (const float*)d_in[5];
    const float* dec2_w    = (const float*)d_in[6];
    const float* dec2_b    = (const float*)d_in[7];
    const float* mlp1_w    = (const float*)d_in[8];
    const float* mlp1_b    = (const float*)d_in[9];
    const float* mlp2_w    = (const float*)d_in[10];
    const float* mlp2_b    = (const float*)d_in[11];
    const float* pool1_w   = (const float*)d_in[12];
    const float* gat_w     = (const float*)d_in[13];
    const float* att_src   = (const float*)d_in[14];
    const float* att_dst   = (const float*)d_in[15];
    const float* gat_b     = (const float*)d_in[16];
    const float* pool2_w   = (const float*)d_in[17];
    const float* lin1_w    = (const float*)d_in[18];
    const float* lin1_b    = (const float*)d_in[19];
    const float* lin2_w    = (const float*)d_in[20];
    const float* lin2_b    = (const float*)d_in[21];
    const float* lin3_w    = (const float*)d_in[22];
    const float* lin3_b    = (const float*)d_in[23];
    const int* srcG = eidx;
    const int* dstG = eidx + E_;
    float* out = (float*)d_out;

    // ---- workspace layout
    char* base = (char*)d_ws;
    size_t o = 0;
    auto alloc = [&](size_t bytes) { size_t r = o; o = (o + bytes + 255) & ~(size_t)255; return r; };
    size_t agg_off    = alloc((size_t)BN_ * 32 * 4);
    size_t cntn_off   = alloc((size_t)BN_ * 4);        // node-CSR counters
    size_t cnt_off    = alloc((size_t)NK_ * 4);        // GAT-CSR counters
    size_t kept_off   = alloc((size_t)BN_ * 4);
    size_t zero_bytes = o;                             // agg + cnt_node + cnt + kept contiguous
    size_t newid_off  = alloc((size_t)BN_ * 4);
    size_t offsn_off  = alloc((size_t)(BN_ + 1) * 4);
    size_t csre_off   = alloc((size_t)E_ * 4);
    size_t h_off      = alloc((size_t)BN_ * 256 * 4);  // also g
    size_t hp_off     = alloc((size_t)NK_ * 256 * 4);
    size_t xl_off     = alloc((size_t)NK_ * 256 * 4);  // also t1 [BN_,128]
    size_t s_off      = alloc((size_t)BN_ * 4);        // also s2
    size_t tnode_off  = alloc((size_t)NK_ * 4);
    size_t tval_off   = alloc((size_t)NK_ * 4);
    size_t offs_off   = alloc((size_t)(NK_ + 1) * 4);
    size_t csr_off    = alloc((size_t)E_ * 4);
    size_t zbuf_off   = alloc((size_t)B_ * 512 * 4);
    size_t asrc_off   = alloc((size_t)NK_ * 4 * 4);
    size_t adst_off   = alloc((size_t)NK_ * 4 * 4);
    size_t norm_off   = alloc(256);
    if (o > ws_size) return;   // workspace too small -> fail validation visibly

    float* agg      = (float*)(base + agg_off);
    int*   cnt_node = (int*)  (base + cntn_off);
    int*   cnt      = (int*)  (base + cnt_off);
    int*   kept     = (int*)  (base + kept_off);
    int*   newid    = (int*)  (base + newid_off);
    int*   offs_n   = (int*)  (base + offsn_off);
    int*   csr_e    = (int*)  (base + csre_off);
    float* h        = (float*)(base + h_off);
    float* g        = h;
    float* hp       = (float*)(base + hp_off);
    float* xl       = (float*)(base + xl_off);
    float* t1       = xl;
    float* s        = (float*)(base + s_off);
    int*   tnode    = (int*)  (base + tnode_off);
    float* tval     = (float*)(base + tval_off);
    int*   offs     = (int*)  (base + offs_off);
    int*   csr      = (int*)  (base + csr_off);
    float* zbuf     = (float*)(base + zbuf_off);
    float* a_src    = (float*)(base + asrc_off);
    float* a_dst    = (float*)(base + adst_off);
    float* norms    = (float*)(base + norm_off);

    hipMemsetAsync(d_ws, 0, zero_bytes, stream);

    norm_kernel<<<1, 256, 0, stream>>>(pool1_w, pool2_w, norms);

    // node-CSR over ALL edges (dst-sorted permutation)
    count_node_kernel<<<E_ / 256, 256, 0, stream>>>(dstG, cnt_node);
    scan_kernel<BN_><<<1, 1024, 0, stream>>>(cnt_node, offs_n);
    fill_node_kernel<<<E_ / 256, 256, 0, stream>>>(dstG, offs_n, cnt_node, csr_e);

    // fused edge MLP + GINE aggregate (dst-sorted, pipelined staging)
    edge_mlp_agg_kernel<<<E_ / 64, 256, 0, stream>>>(edge_attr, srcG, dstG, csr_e, x,
                                                     dec1_w, dec1_b, dec2_w, dec2_b, agg);

    // MLP1: t1 = relu((x+agg) @ mlp1_w + b)   [BN_,128]
    gemm_tile128<1, true, true><<<dim3(128 / 128, BN_ / 128), 256, 0, stream>>>(
        x, agg, mlp1_w, mlp1_b, t1, BN_, 128, 32);
    // MLP2: h = relu(t1 @ mlp2_w + b)         [BN_,256]
    gemm_tile128<1, true, false><<<dim3(256 / 128, BN_ / 128), 256, 0, stream>>>(
        t1, nullptr, mlp2_w, mlp2_b, h, BN_, 256, 128);

    scores_kernel<<<BN_ / 4, 256, 0, stream>>>(h, pool1_w, norms, 0, s, BN_);
    topk1_kernel<<<B_, 512, 0, stream>>>(s, tval, tnode, kept, newid);
    gather_scale_kernel<<<(NK_ * 64) / 256, 256, 0, stream>>>(h, tnode, tval, hp);
    readout1_kernel<<<B_, 1024, 0, stream>>>(hp, zbuf);

    // GAT transform: xl = hp @ gat_w          [NK_,256]
    gemm_tile128<0, false, false><<<dim3(256 / 128, NK_ / 128), 256, 0, stream>>>(
        hp, nullptr, gat_w, nullptr, xl, NK_, 256, 256);
    attcoef_kernel<<<NK_ / 4, 256, 0, stream>>>(xl, att_src, att_dst, a_src, a_dst);

    count_kernel<<<E_ / 256, 256, 0, stream>>>(srcG, dstG, kept, newid, cnt);
    scan_kernel<NK_><<<1, 1024, 0, stream>>>(cnt, offs);
    fill_kernel<<<E_ / 256, 256, 0, stream>>>(srcG, dstG, kept, newid, offs, cnt, csr);

    gat_agg_kernel<<<NK_ / 4, 256, 0, stream>>>(xl, a_src, a_dst, offs, csr, gat_b, g);

    scores_kernel<<<NK_ / 4, 256, 0, stream>>>(g, pool2_w, norms, 1, s, NK_);
    topk2_readout_kernel<<<B_, 512, 0, stream>>>(s, g, zbuf);

    head_kernel<<<B_, 128, 0, stream>>>(zbuf, lin1_w, lin1_b, lin2_w, lin2_b,
                                        lin3_w, lin3_b, out);
}